// Round 9
// baseline (226.242 us; speedup 1.0000x reference)
//
#include <hip/hip_runtime.h>
#include <hip/hip_bf16.h>
#include <stdint.h>

typedef unsigned short u16;
typedef __attribute__((ext_vector_type(8))) short short8_t;
typedef __attribute__((ext_vector_type(4))) float f32x4;

#define D_DIM 512
#define K_CL  256
#define BM    128
#define BK    64
#define NSTEP 8

__device__ __forceinline__ u16 f2bf(float f) {
  union { float f; uint32_t u; } v; v.f = f;
  uint32_t r = v.u + 0x7fffu + ((v.u >> 16) & 1u);  // RNE
  return (u16)(r >> 16);
}

__device__ __forceinline__ short8_t pack8(const float4& f0, const float4& f1) {
  union { __hip_bfloat16 h[8]; short8_t v; } pk;
  pk.h[0] = __float2bfloat16(f0.x); pk.h[1] = __float2bfloat16(f0.y);
  pk.h[2] = __float2bfloat16(f0.z); pk.h[3] = __float2bfloat16(f0.w);
  pk.h[4] = __float2bfloat16(f1.x); pk.h[5] = __float2bfloat16(f1.y);
  pk.h[6] = __float2bfloat16(f1.z); pk.h[7] = __float2bfloat16(f1.w);
  return pk.v;
}

__device__ __forceinline__ void gload(const u16* src, char* dst) {
  __builtin_amdgcn_global_load_lds(
      (const __attribute__((address_space(1))) void*)src,
      (__attribute__((address_space(3))) void*)dst, 16, 0, 0);
}

// prep: clusters fp32 [256][512] -> bf16 cb [256][512] + csq[256] (fp32 norms)
__global__ void prep_kernel(const float* __restrict__ clusters,
                            u16* __restrict__ cb, float* __restrict__ csq) {
  int k = blockIdx.x;
  int t = threadIdx.x;  // 128 threads, 4 floats each
  float4 f = ((const float4*)(clusters + (size_t)k * D_DIM))[t];
  ushort4 u;
  u.x = f2bf(f.x); u.y = f2bf(f.y); u.z = f2bf(f.z); u.w = f2bf(f.w);
  ((ushort4*)(cb + (size_t)k * D_DIM))[t] = u;
  float s = f.x*f.x + f.y*f.y + f.z*f.z + f.w*f.w;
  #pragma unroll
  for (int m = 1; m < 64; m <<= 1) s += __shfl_xor(s, m, 64);
  __shared__ float part[2];
  if ((t & 63) == 0) part[t >> 6] = s;
  __syncthreads();
  if (t == 0) csq[k] = part[0] + part[1];
}

// main: 8 waves x 16 rows (R1 shape), x FRONT-LOADED in two 16-load bursts
// decoupled from the K-loop. Main loop has ZERO A-loads/packs: 4 gload_lds +
// 32 swizzled ds_read + 32 MFMA + barrier per step. (512,2): ~195 VGPR, no
// spill, 1 block/CU. All data-path math verbatim from verified R1/R8.
__global__ __launch_bounds__(512, 2)
void cluster_kernel(const float* __restrict__ x,
                    const u16* __restrict__ cb,
                    const float* __restrict__ csq,
                    float* __restrict__ out) {
  __shared__ __align__(128) u16 lB[2 * K_CL * BK];   // 64 KB double buffer

  const int tid  = threadIdx.x;       // 512 threads
  const int lane = tid & 63;
  const int w    = tid >> 6;          // wave 0..7 -> 16-row stripe
  const int l16  = lane & 15;
  const int quad = lane >> 4;
  const int row0 = blockIdx.x * BM;

  // ---- A: lane owns row (w*16+l16), quad-slice: floats j*32+quad*8 .. +8 ----
  const float4* xg = (const float4*)(x + (size_t)(row0 + w * 16 + l16) * D_DIM + quad * 8);

  // ---- B staging sources, pre-swizzled (verified R1 math); dest linear ----
  const int o0   = tid * 16;
  const int n0   = o0 >> 7;
  const int skb0 = (o0 & 127) ^ ((n0 & 7) << 4);
  const int o1   = 8192 + tid * 16;
  const int n1   = o1 >> 7;
  const int skb1 = (o1 & 127) ^ ((n1 & 7) << 4);
  const u16* sp0 = cb + (size_t)n0 * D_DIM + (skb0 >> 1);
  const u16* sp1 = cb + (size_t)n1 * D_DIM + (skb1 >> 1);

  // ---- swizzled ds_read byte offsets (verified R1 math) ----
  const int c3 = (l16 & 3) << 4;
  const int h  = (l16 & 4) << 4;
  const int p  = l16 * 128 + ((quad * 16) ^ c3);
  const int p0 = p + h;           // k32 = 0
  const int p1 = p + (h ^ 64);    // k32 = 1

  f32x4 acc[16];
  #pragma unroll
  for (int i = 0; i < 16; ++i) acc[i] = (f32x4){0.f, 0.f, 0.f, 0.f};

  float sq = 0.f;
  float4 raw[16];
  short8_t aA[8], aB[8];

  // ---- prologue: stage(0) + x burst-1 (steps 0-3) + pack-1 ----
  {
    char* dstb = (char*)lB + tid * 16;
    gload(sp0, dstb);
    gload(sp1, dstb + 8192);
    gload(sp0 + 65536, dstb + 16384);
    gload(sp1 + 65536, dstb + 24576);
  }
  #pragma unroll
  for (int j = 0; j < 8; ++j) { raw[2*j] = xg[j*8]; raw[2*j+1] = xg[j*8+1]; }
  #pragma unroll
  for (int j = 0; j < 8; ++j) {
    const float4 f0 = raw[2*j], f1 = raw[2*j+1];
    sq += f0.x*f0.x + f0.y*f0.y + f0.z*f0.z + f0.w*f0.w
        + f1.x*f1.x + f1.y*f1.y + f1.z*f1.z + f1.w*f1.w;
    aA[j] = pack8(f0, f1);
  }
  __syncthreads();   // buf0 staged (x burst drained by pack's own waits)

  // per-step body: stage(next) + 32 swizzled ds_read_b128 + 32 MFMA + barrier
  #define KSTEP(STEP, AF0, AF1)                                               \
  {                                                                           \
    if ((STEP) + 1 < NSTEP) {                                                 \
      const u16* q0 = sp0 + ((STEP) + 1) * BK;                                \
      const u16* q1 = sp1 + ((STEP) + 1) * BK;                                \
      char* dstb = (char*)lB + ((((STEP) + 1) & 1) << 15) + tid * 16;         \
      gload(q0, dstb);                                                        \
      gload(q1, dstb + 8192);                                                 \
      gload(q0 + 65536, dstb + 16384);                                        \
      gload(q1 + 65536, dstb + 24576);                                        \
    }                                                                         \
    const char* pb = (const char*)lB + (((STEP) & 1) << 15);                  \
    _Pragma("unroll")                                                         \
    for (int ni = 0; ni < 16; ++ni) {                                         \
      short8_t b0 = *(const short8_t*)(pb + ni * 2048 + p0);                  \
      short8_t b1 = *(const short8_t*)(pb + ni * 2048 + p1);                  \
      acc[ni] = __builtin_amdgcn_mfma_f32_16x16x32_bf16(AF0, b0, acc[ni], 0, 0, 0); \
      acc[ni] = __builtin_amdgcn_mfma_f32_16x16x32_bf16(AF1, b1, acc[ni], 0, 0, 0); \
    }                                                                         \
    if ((STEP) + 1 < NSTEP) __syncthreads();                                  \
  }

  // ---- step 0: issue x burst-2 FIRST (ages across step 0, drains at barrier) ----
  #pragma unroll
  for (int j = 0; j < 8; ++j) { raw[2*j] = xg[64 + j*8]; raw[2*j+1] = xg[64 + j*8 + 1]; }
  KSTEP(0, aA[0], aA[1])

  // ---- step 1: pack burst-2 (raw drained at step-0 barrier) ----
  #pragma unroll
  for (int j = 0; j < 8; ++j) {
    const float4 f0 = raw[2*j], f1 = raw[2*j+1];
    sq += f0.x*f0.x + f0.y*f0.y + f0.z*f0.z + f0.w*f0.w
        + f1.x*f1.x + f1.y*f1.y + f1.z*f1.z + f1.w*f1.w;
    aB[j] = pack8(f0, f1);
  }
  KSTEP(1, aA[2], aA[3])
  KSTEP(2, aA[4], aA[5])
  KSTEP(3, aA[6], aA[7])
  KSTEP(4, aB[0], aB[1])
  KSTEP(5, aB[2], aB[3])
  KSTEP(6, aB[4], aB[5])
  KSTEP(7, aB[6], aB[7])
  #undef KSTEP

  // ---- epilogue (wave-local, verified R1 path) ----
  sq += __shfl_xor(sq, 16, 64);
  sq += __shfl_xor(sq, 32, 64);
  // C layout: row = quad*4 + v, col = ni*16 + l16
  float xs[4];
  #pragma unroll
  for (int v = 0; v < 4; ++v)
    xs[v] = __shfl(sq, quad * 4 + v, 64);

  float cs[16];
  #pragma unroll
  for (int ni = 0; ni < 16; ++ni) cs[ni] = csq[ni * 16 + l16];

  float rs[4] = {0.f, 0.f, 0.f, 0.f};
  #pragma unroll
  for (int ni = 0; ni < 16; ++ni) {
    #pragma unroll
    for (int v = 0; v < 4; ++v) {
      float d = xs[v] + cs[ni] - 2.0f * acc[ni][v];
      d = fmaxf(d, 0.f);
      float qv = __builtin_amdgcn_rcpf(1.0f + d);   // alpha=1: (1+d^2)^-1
      acc[ni][v] = qv;
      rs[v] += qv;
    }
  }
  #pragma unroll
  for (int v = 0; v < 4; ++v) {
    rs[v] += __shfl_xor(rs[v], 1, 64);
    rs[v] += __shfl_xor(rs[v], 2, 64);
    rs[v] += __shfl_xor(rs[v], 4, 64);
    rs[v] += __shfl_xor(rs[v], 8, 64);
    rs[v] = __builtin_amdgcn_rcpf(rs[v]);
  }
  #pragma unroll
  for (int v = 0; v < 4; ++v) {
    float* orow = out + (size_t)(row0 + w * 16 + quad * 4 + v) * K_CL;
    #pragma unroll
    for (int ni = 0; ni < 16; ++ni)
      orow[ni * 16 + l16] = acc[ni][v] * rs[v];
  }
}

extern "C" void kernel_launch(void* const* d_in, const int* in_sizes, int n_in,
                              void* d_out, int out_size, void* d_ws, size_t ws_size,
                              hipStream_t stream) {
  const float* x        = (const float*)d_in[0];
  const float* clusters = (const float*)d_in[1];
  float* out = (float*)d_out;
  const int N = in_sizes[0] / D_DIM;   // 65536

  u16*   cb  = (u16*)d_ws;                                    // 256*512*2 = 256 KB
  float* csq = (float*)((char*)d_ws + (size_t)K_CL * D_DIM * sizeof(u16));

  prep_kernel<<<K_CL, 128, 0, stream>>>(clusters, cb, csq);
  cluster_kernel<<<N / BM, 512, 0, stream>>>(x, cb, csq, out);
}